// Round 2
// baseline (383.505 us; speedup 1.0000x reference)
//
#include <hip/hip_runtime.h>
#include <hip/hip_bf16.h>
#include <math.h>

typedef __bf16 bf16x4 __attribute__((ext_vector_type(4)));
typedef __bf16 bf16x8 __attribute__((ext_vector_type(8)));
typedef float f32x4 __attribute__((ext_vector_type(4)));

#define MFMA16(a, b, c) __builtin_amdgcn_mfma_f32_16x16x32_bf16(a, b, c, 0, 0, 0)

// ---------------------------------------------------------------------------
// Kernel 0: convert X fp32 -> bf16, 4 elems/thread (float4 in, bf16x4 out)
// ---------------------------------------------------------------------------
__global__ __launch_bounds__(256) void convert_x(const float* __restrict__ in,
                                                 __bf16* __restrict__ out) {
  int i = blockIdx.x * 256 + threadIdx.x;
  float4 v = ((const float4*)in)[i];
  bf16x4 o = {(__bf16)v.x, (__bf16)v.y, (__bf16)v.z, (__bf16)v.w};
  *(bf16x4*)&out[i * 4] = o;
}

// ---------------------------------------------------------------------------
// Kernel 1: transpose+convert W fp32 [1024,3072] -> Wt bf16 [3072,1024]
// ---------------------------------------------------------------------------
__global__ __launch_bounds__(256) void transpose_w(const float* __restrict__ W,
                                                   __bf16* __restrict__ Wt) {
  __shared__ __bf16 tile[64][65];  // +1 pad: classic transpose conflict fix
  const int bx = blockIdx.x;       // n tile (48)
  const int by = blockIdx.y;       // k tile (16)
  const int t = threadIdx.x;
  const int lr = t >> 6;   // 0..3
  const int lc = t & 63;   // 0..63
#pragma unroll
  for (int i = 0; i < 16; ++i) {
    int r = lr + i * 4;
    tile[r][lc] = (__bf16)W[(size_t)(by * 64 + r) * 3072 + bx * 64 + lc];
  }
  __syncthreads();
#pragma unroll
  for (int i = 0; i < 16; ++i) {
    int r = lr + i * 4;
    Wt[(size_t)(bx * 64 + r) * 1024 + by * 64 + lc] = tile[lc][r];
  }
}

// ---------------------------------------------------------------------------
// Kernel 2: QKV = X @ W  as  QKV[m][n] = sum_k Xb[m][k] * Wt[n][k]
//   Xb [8192,1024], Wt [3072,1024], QKV [8192,3072], all bf16.
//   128x128 tile, BK=32, 4 waves each computing 64x64 via 4x4 MFMA 16x16x32.
// ---------------------------------------------------------------------------
#define TM 128
#define TN 128
#define BK 32
#define LDA 48  // padded LDS row stride (96B, 16B-aligned, breaks 64B-stride conflicts)

__global__ __launch_bounds__(256) void gemm_qkv(const __bf16* __restrict__ X,
                                                const __bf16* __restrict__ Wt,
                                                __bf16* __restrict__ QKV) {
  __shared__ __bf16 As[TM * LDA];
  __shared__ __bf16 Bs[TN * LDA];
  const int n0 = blockIdx.x * TN;
  const int m0 = blockIdx.y * TM;
  const int t = threadIdx.x;
  const int lane = t & 63;
  const int wave = t >> 6;
  const int quad = lane >> 4;
  const int l16 = lane & 15;
  const int wm = (wave & 1) * 64;
  const int wn = (wave >> 1) * 64;
  const int sr = t >> 2;        // staging row 0..63
  const int sk = (t & 3) * 8;   // staging k-chunk

  f32x4 acc[4][4] = {};

  for (int k0 = 0; k0 < 1024; k0 += BK) {
    // global -> regs (overlaps with previous tile's MFMA before the barrier)
    bf16x8 a0 = *(const bf16x8*)&X[(size_t)(m0 + sr) * 1024 + k0 + sk];
    bf16x8 a1 = *(const bf16x8*)&X[(size_t)(m0 + sr + 64) * 1024 + k0 + sk];
    bf16x8 b0 = *(const bf16x8*)&Wt[(size_t)(n0 + sr) * 1024 + k0 + sk];
    bf16x8 b1 = *(const bf16x8*)&Wt[(size_t)(n0 + sr + 64) * 1024 + k0 + sk];
    __syncthreads();
    *(bf16x8*)&As[sr * LDA + sk] = a0;
    *(bf16x8*)&As[(sr + 64) * LDA + sk] = a1;
    *(bf16x8*)&Bs[sr * LDA + sk] = b0;
    *(bf16x8*)&Bs[(sr + 64) * LDA + sk] = b1;
    __syncthreads();

    bf16x8 af[4], bf[4];
#pragma unroll
    for (int mi = 0; mi < 4; ++mi)
      af[mi] = *(const bf16x8*)&As[(wm + mi * 16 + l16) * LDA + quad * 8];
#pragma unroll
    for (int ni = 0; ni < 4; ++ni)
      bf[ni] = *(const bf16x8*)&Bs[(wn + ni * 16 + l16) * LDA + quad * 8];
#pragma unroll
    for (int mi = 0; mi < 4; ++mi)
#pragma unroll
      for (int ni = 0; ni < 4; ++ni)
        acc[mi][ni] = MFMA16(af[mi], bf[ni], acc[mi][ni]);
  }

  // epilogue: C/D layout col=lane&15, row=(lane>>4)*4+r  [m89/m91-verified]
#pragma unroll
  for (int mi = 0; mi < 4; ++mi)
#pragma unroll
    for (int ni = 0; ni < 4; ++ni)
#pragma unroll
      for (int r = 0; r < 4; ++r) {
        int row = m0 + wm + mi * 16 + quad * 4 + r;
        int col = n0 + wn + ni * 16 + l16;
        QKV[(size_t)row * 3072 + col] = (__bf16)acc[mi][ni][r];
      }
}

// ---------------------------------------------------------------------------
// Kernel 3: flash attention.
//   QKV [4*2048, 3072] bf16 rows = [Q | K | V] each 1024 = 16 heads x 64.
//   Block = (q-tile of 64 rows, head, batch); 4 waves, each owns 16 q-rows.
//   Per 64-key KV tile: S=QK^T (MFMA), online softmax, O += P V (MFMA).
// ---------------------------------------------------------------------------
#define KS_LD 72  // padded strides: 144B rows, 16B-aligned, conflict-reduced
#define VT_LD 72
#define PS_LD 72

__global__ __launch_bounds__(256) void attn(const __bf16* __restrict__ QKV,
                                            float* __restrict__ Out) {
  const int q0 = blockIdx.x * 64;
  const int h = blockIdx.y;
  const int b = blockIdx.z;
  const int t = threadIdx.x;
  const int lane = t & 63;
  const int wave = t >> 6;
  const int quad = lane >> 4;
  const int l16 = lane & 15;

  const size_t base = (size_t)b * 2048 * 3072;
  const __bf16* Qb = QKV + base + h * 64;
  const __bf16* Kb = QKV + base + 1024 + h * 64;
  const __bf16* Vb = QKV + base + 2048 + h * 64;

  __shared__ __bf16 Ks[64 * KS_LD];      // [key][d]
  __shared__ __bf16 Vt[64 * VT_LD];      // [d][key]  (transposed for B-fragment)
  __shared__ __bf16 Ps[4][16 * PS_LD];   // per-wave P, [qrow][key]

  // Q fragments (A-operand: A[m=l16][k=quad*8+j]), loaded once from global
  const int qrow = q0 + wave * 16 + l16;
  bf16x8 qf0 = *(const bf16x8*)&Qb[(size_t)qrow * 3072 + quad * 8];
  bf16x8 qf1 = *(const bf16x8*)&Qb[(size_t)qrow * 3072 + 32 + quad * 8];

  f32x4 o[4] = {};
  float mrow[4], lrow[4];
#pragma unroll
  for (int r = 0; r < 4; ++r) { mrow[r] = -1e30f; lrow[r] = 0.0f; }

  const int sr = t >> 2;        // K staging: row 0..63
  const int sd = (t & 3) * 16;  // K staging: d-chunk

  for (int kv0 = 0; kv0 < 2048; kv0 += 64) {
    // global -> regs
    bf16x8 k0v = *(const bf16x8*)&Kb[(size_t)(kv0 + sr) * 3072 + sd];
    bf16x8 k1v = *(const bf16x8*)&Kb[(size_t)(kv0 + sr) * 3072 + sd + 8];
    // V: lane reads key=lane, d-chunk = wave*16 (transpose-friendly mapping)
    bf16x8 v0v = *(const bf16x8*)&Vb[(size_t)(kv0 + lane) * 3072 + wave * 16];
    bf16x8 v1v = *(const bf16x8*)&Vb[(size_t)(kv0 + lane) * 3072 + wave * 16 + 8];
    __syncthreads();  // previous iter's PV reads of Ks/Vt are done
    *(bf16x8*)&Ks[sr * KS_LD + sd] = k0v;
    *(bf16x8*)&Ks[sr * KS_LD + sd + 8] = k1v;
#pragma unroll
    for (int i = 0; i < 8; ++i) Vt[(wave * 16 + i) * VT_LD + lane] = v0v[i];
#pragma unroll
    for (int i = 0; i < 8; ++i) Vt[(wave * 16 + 8 + i) * VT_LD + lane] = v1v[i];
    __syncthreads();

    // S = Q K^T : this wave's 16 q-rows x 64 keys
    f32x4 s[4];
#pragma unroll
    for (int nt = 0; nt < 4; ++nt) {
      bf16x8 kf0 = *(const bf16x8*)&Ks[(nt * 16 + l16) * KS_LD + quad * 8];
      bf16x8 kf1 = *(const bf16x8*)&Ks[(nt * 16 + l16) * KS_LD + 32 + quad * 8];
      f32x4 z = {};
      z = MFMA16(qf0, kf0, z);
      z = MFMA16(qf1, kf1, z);
      s[nt] = z;
    }

    // online softmax; row = quad*4+r, cols spread over 16 lanes x 4 nt
    float p[4][4];
#pragma unroll
    for (int r = 0; r < 4; ++r) {
      float mx = -1e30f;
#pragma unroll
      for (int nt = 0; nt < 4; ++nt) {
        s[nt][r] *= 0.125f;  // DIM_HEAD^-0.5
        mx = fmaxf(mx, s[nt][r]);
      }
#pragma unroll
      for (int off = 1; off < 16; off <<= 1) mx = fmaxf(mx, __shfl_xor(mx, off));
      float newm = fmaxf(mrow[r], mx);
      float alpha = __expf(mrow[r] - newm);
      mrow[r] = newm;
      float rs = 0.0f;
#pragma unroll
      for (int nt = 0; nt < 4; ++nt) {
        p[nt][r] = __expf(s[nt][r] - newm);
        rs += p[nt][r];
      }
#pragma unroll
      for (int off = 1; off < 16; off <<= 1) rs += __shfl_xor(rs, off);
      lrow[r] = lrow[r] * alpha + rs;
#pragma unroll
      for (int nt = 0; nt < 4; ++nt) o[nt][r] *= alpha;
    }

    // P: C-layout regs -> LDS -> A-layout fragments (m120-verified round-trip)
#pragma unroll
    for (int nt = 0; nt < 4; ++nt)
#pragma unroll
      for (int r = 0; r < 4; ++r)
        Ps[wave][(quad * 4 + r) * PS_LD + nt * 16 + l16] = (__bf16)p[nt][r];
    __syncthreads();

    bf16x8 pf0 = *(const bf16x8*)&Ps[wave][l16 * PS_LD + quad * 8];
    bf16x8 pf1 = *(const bf16x8*)&Ps[wave][l16 * PS_LD + 32 + quad * 8];
#pragma unroll
    for (int nt = 0; nt < 4; ++nt) {
      bf16x8 vf0 = *(const bf16x8*)&Vt[(nt * 16 + l16) * VT_LD + quad * 8];
      bf16x8 vf1 = *(const bf16x8*)&Vt[(nt * 16 + l16) * VT_LD + 32 + quad * 8];
      o[nt] = MFMA16(pf0, vf0, o[nt]);
      o[nt] = MFMA16(pf1, vf1, o[nt]);
    }
  }

  // epilogue: out[b][n][h*64+d] fp32, divide by softmax denominator
#pragma unroll
  for (int r = 0; r < 4; ++r) {
    float inv = 1.0f / lrow[r];
    int orow = b * 2048 + q0 + wave * 16 + quad * 4 + r;
#pragma unroll
    for (int nt = 0; nt < 4; ++nt)
      Out[(size_t)orow * 1024 + h * 64 + nt * 16 + l16] = o[nt][r] * inv;
  }
}

// ---------------------------------------------------------------------------
extern "C" void kernel_launch(void* const* d_in, const int* in_sizes, int n_in,
                              void* d_out, int out_size, void* d_ws, size_t ws_size,
                              hipStream_t stream) {
  const float* x = (const float*)d_in[0];        // [4,2048,1024] fp32
  const float* w = (const float*)d_in[1];        // [1024,3072]  fp32
  float* out = (float*)d_out;                    // [4,2048,1024] fp32

  __bf16* Wt = (__bf16*)d_ws;                    // [3072,1024]   6.29 MB
  __bf16* QKV = Wt + (size_t)3072 * 1024;        // [8192,3072]  50.33 MB
  __bf16* Xb = QKV + (size_t)8192 * 3072;        // [8192,1024]  16.78 MB

  convert_x<<<8192, 256, 0, stream>>>(x, Xb);
  transpose_w<<<dim3(48, 16), 256, 0, stream>>>(w, Wt);
  gemm_qkv<<<dim3(24, 64), 256, 0, stream>>>(Xb, Wt, QKV);
  attn<<<dim3(32, 16, 4), 256, 0, stream>>>(QKV, out);
}